// Round 2
// baseline (327.930 us; speedup 1.0000x reference)
//
#include <hip/hip_runtime.h>
#include <cmath>

// Sliding-window min over time, window W=64, per column.
// signal: [T, D] fp32 row-major.  out[t][d] = min(signal[max(0,t-63)..t][d]).
// Van Herk / Gil-Werman: per 64-row block, out = min(prev-block suffix-min,
// current-block running prefix-min).
//
// R1 lesson: the b-loop must be fully unrolled — otherwise SROA leaves A[64]
// in scratch (VGPR_Count=48 observed) and the kernel is scratch-latency-bound
// at 173 us. All A[] indices must be compile-time constants.

constexpr int T_DIM = 4096;
constexpr int D_DIM = 8192;
constexpr int W = 64;        // window / block length
constexpr int TSEG = 256;    // time rows per workgroup (4 blocks of 64)
constexpr int NB = TSEG / W;
constexpr int THREADS = 256;

__global__ __launch_bounds__(THREADS)
void TemporalOperator_74182675136668_kernel(const float* __restrict__ in,
                                            float* __restrict__ out) {
    const int col = blockIdx.x * THREADS + threadIdx.x;   // one column per thread
    const int t0 = blockIdx.y * TSEG;                     // segment start row
    const float* pin = in + col;
    float* pout = out + col;

    // A[] dual-purpose: suffix-mins of previous 64-block (read at i+1 on iter i),
    // then overwritten in place with current block's raw values (write at i).
    float A[W];

    if (t0 == 0) {
#pragma unroll
        for (int i = 0; i < W; ++i) A[i] = INFINITY;
    } else {
        // Prime: load the 64 rows preceding this segment, build suffix mins.
#pragma unroll
        for (int i = 0; i < W; ++i) A[i] = pin[(t0 - W + i) * D_DIM];
#pragma unroll
        for (int i = W - 2; i >= 0; --i) A[i] = fminf(A[i], A[i + 1]);
    }

#pragma unroll
    for (int b = 0; b < NB; ++b) {
        const int tb = t0 + b * W;
        float L = INFINITY;  // running prefix min of current block
#pragma unroll
        for (int i = 0; i < W; ++i) {
            const float xi = pin[(tb + i) * D_DIM];
            L = fminf(L, xi);
            // window [tb+i-63, tb+i] = prev-block rows [i+1..63] + cur rows [0..i]
            const float o = (i + 1 < W) ? fminf(L, A[i + 1]) : L;
            __builtin_nontemporal_store(o, &pout[(tb + i) * D_DIM]);
            A[i] = xi;  // slot i is dead (consumed on iter i-1) — stage raw value
        }
        // Turn staged raw values into suffix mins for the next block.
#pragma unroll
        for (int i = W - 2; i >= 0; --i) A[i] = fminf(A[i], A[i + 1]);
    }
}

extern "C" void kernel_launch(void* const* d_in, const int* in_sizes, int n_in,
                              void* d_out, int out_size, void* d_ws, size_t ws_size,
                              hipStream_t stream) {
    const float* in = (const float*)d_in[0];
    float* out = (float*)d_out;
    dim3 grid(D_DIM / THREADS, T_DIM / TSEG);  // 32 x 16 = 512 blocks
    TemporalOperator_74182675136668_kernel<<<grid, THREADS, 0, stream>>>(in, out);
}

// Round 3
// 241.736 us; speedup vs baseline: 1.3566x; 1.3566x over previous
//
#include <hip/hip_runtime.h>
#include <cmath>

// Sliding-window min over time, window W=64, per column.
// out[t][d] = min(signal[max(0,t-63)..t][d]).  Van Herk / Gil-Werman.
//
// R1/R2 lesson: with default launch bounds the AMDGPU regalloc targets high
// occupancy and SPILLS the 64-deep suffix-min array to scratch (VGPR_Count
// observed 44-48) -> scratch-latency-bound at 173 us regardless of unrolling.
// __launch_bounds__(256, 2) grants a ~256-VGPR budget so A[64] stays in
// registers; loads are staged in 16-wide batches for memory-level parallelism.

constexpr int T_DIM = 4096;
constexpr int D_DIM = 8192;
constexpr int W = 64;        // window / block length
constexpr int TSEG = 128;    // time rows per workgroup (2 blocks of 64)
constexpr int NB = TSEG / W;
constexpr int CHUNK = 16;    // load-staging batch
constexpr int THREADS = 256;

__global__ __launch_bounds__(THREADS, 2)
void TemporalOperator_74182675136668_kernel(const float* __restrict__ in,
                                            float* __restrict__ out) {
    const int col = blockIdx.x * THREADS + threadIdx.x;   // one column per thread
    const int t0 = blockIdx.y * TSEG;                     // segment start row
    const float* pin = in + col;
    float* pout = out + col;

    // A[] dual-purpose: suffix-mins of previous 64-block (read at i+1 on iter i),
    // then overwritten in place with current block's raw values (write at i).
    float A[W];

    if (t0 == 0) {
#pragma unroll
        for (int i = 0; i < W; ++i) A[i] = INFINITY;
    } else {
        // Prime: load the 64 rows preceding this segment, build suffix mins.
#pragma unroll
        for (int i = 0; i < W; ++i) A[i] = pin[(t0 - W + i) * D_DIM];
#pragma unroll
        for (int i = W - 2; i >= 0; --i) A[i] = fminf(A[i], A[i + 1]);
    }

#pragma unroll
    for (int b = 0; b < NB; ++b) {
        const int tb = t0 + b * W;
        float L = INFINITY;  // running prefix min of current block
#pragma unroll
        for (int c = 0; c < W / CHUNK; ++c) {
            // Batch 16 independent loads, THEN consume -> 16 loads in flight.
            float X[CHUNK];
#pragma unroll
            for (int j = 0; j < CHUNK; ++j)
                X[j] = pin[(tb + c * CHUNK + j) * D_DIM];
#pragma unroll
            for (int j = 0; j < CHUNK; ++j) {
                const int i = c * CHUNK + j;
                L = fminf(L, X[j]);
                // window [tb+i-63, tb+i] = prev rows [i+1..63] + cur rows [0..i]
                const float o = (i + 1 < W) ? fminf(L, A[i + 1]) : L;
                __builtin_nontemporal_store(o, &pout[(tb + i) * D_DIM]);
                A[i] = X[j];  // slot i is dead (consumed on iter i-1)
            }
        }
        // Turn staged raw values into suffix mins for the next block.
#pragma unroll
        for (int i = W - 2; i >= 0; --i) A[i] = fminf(A[i], A[i + 1]);
    }
}

extern "C" void kernel_launch(void* const* d_in, const int* in_sizes, int n_in,
                              void* d_out, int out_size, void* d_ws, size_t ws_size,
                              hipStream_t stream) {
    const float* in = (const float*)d_in[0];
    float* out = (float*)d_out;
    dim3 grid(D_DIM / THREADS, T_DIM / TSEG);  // 32 x 32 = 1024 blocks
    TemporalOperator_74182675136668_kernel<<<grid, THREADS, 0, stream>>>(in, out);
}